// Round 1
// baseline (1308.914 us; speedup 1.0000x reference)
//
#include <hip/hip_runtime.h>

#define N_NODES 20000
#define N_EDGES 320000
#define F_DIM   128
#define H_DIM   256
#define M_ROWS  4096
#define NQ      2048
#define NIT     48

// ---------------- helpers ----------------

__device__ __forceinline__ float wred(float v) {
#pragma unroll
  for (int m = 32; m > 0; m >>= 1) v += __shfl_xor(v, m, 64);
  return v;
}

// block of 256 threads -> total broadcast to all threads
__device__ __forceinline__ float bred256(float v, float* lds) {
  v = wred(v);
  int w = threadIdx.x >> 6;
  if ((threadIdx.x & 63) == 0) lds[w] = v;
  __syncthreads();
  float tot = lds[0] + lds[1] + lds[2] + lds[3];
  __syncthreads();
  return tot;
}

// ---------------- CSR build ----------------

__global__ __launch_bounds__(256) void k_deg(const int* __restrict__ ei, int* __restrict__ deg) {
  int e = blockIdx.x * 256 + threadIdx.x;
  if (e < N_EDGES) atomicAdd(&deg[ei[e]], 1);
}

__global__ __launch_bounds__(256) void k_dinv(const int* __restrict__ deg, float* __restrict__ dinv) {
  int i = blockIdx.x * 256 + threadIdx.x;
  if (i < N_NODES) {
    int d = deg[i];
    dinv[i] = d > 0 ? rsqrtf((float)d) : 0.f;
  }
}

__global__ __launch_bounds__(1024) void k_scan(const int* __restrict__ deg, int* __restrict__ rowstart) {
  __shared__ int part[1024];
  int t = threadIdx.x;
  const int chunk = (N_NODES + 1023) / 1024;  // 20
  int lo = t * chunk;
  int hi = lo + chunk; if (hi > N_NODES) hi = N_NODES;
  int s = 0;
  for (int i = lo; i < hi; ++i) s += deg[i];
  part[t] = s;
  __syncthreads();
  for (int off = 1; off < 1024; off <<= 1) {
    int v = part[t];
    int add = (t >= off) ? part[t - off] : 0;
    __syncthreads();
    part[t] = v + add;
    __syncthreads();
  }
  int base = (t > 0) ? part[t - 1] : 0;
  for (int i = lo; i < hi; ++i) { rowstart[i] = base; base += deg[i]; }
  if (t == 0) rowstart[N_NODES] = part[1023];
}

__global__ __launch_bounds__(256) void k_scatter(const int* __restrict__ ei,
    const int* __restrict__ rowstart, int* __restrict__ cursor,
    const float* __restrict__ dinv, int* __restrict__ cols, float* __restrict__ wvals) {
  int e = blockIdx.x * 256 + threadIdx.x;
  if (e >= N_EDGES) return;
  int r = ei[e];
  int c = ei[N_EDGES + e];
  int pos = rowstart[r] + atomicAdd(&cursor[r], 1);
  cols[pos] = c;
  wvals[pos] = -dinv[r] * dinv[c];
}

// ---------------- GNN layer 1 ----------------

// one wave per row: msg[i,:] = sum_e w_e * x[col_e,:]
__global__ __launch_bounds__(256) void k_msg1(const float* __restrict__ x,
    const int* __restrict__ rowstart, const int* __restrict__ cols,
    const float* __restrict__ wvals, float* __restrict__ msg) {
  int wid = (blockIdx.x * 256 + threadIdx.x) >> 6;
  int lane = threadIdx.x & 63;
  if (wid >= N_NODES) return;
  int s0 = rowstart[wid], s1 = rowstart[wid + 1];
  const float2* x2 = (const float2*)x;
  float2 acc = make_float2(0.f, 0.f);
  for (int e = s0; e < s1; ++e) {
    int c = cols[e];
    float w = wvals[e];
    float2 xv = x2[(size_t)c * 64 + lane];
    acc.x += w * xv.x;
    acc.y += w * xv.y;
  }
  ((float2*)msg)[(size_t)wid * 64 + lane] = acc;
}

// h = relu(x@W10 + msg@W11 + b1);  64x64 tile, 4x4/thread, fp32
__global__ __launch_bounds__(256) void k_gemm1(const float* __restrict__ x,
    const float* __restrict__ msg, const float* __restrict__ W10,
    const float* __restrict__ W11, const float* __restrict__ b1, float* __restrict__ h) {
  __shared__ float As[32][68];
  __shared__ float Bs[32][68];
  const int row0 = blockIdx.x * 64;
  const int col0 = blockIdx.y * 64;
  const int tid = threadIdx.x;
  const int tx = tid & 15, ty = tid >> 4;
  float acc[4][4] = {};
  for (int pass = 0; pass < 2; ++pass) {
    const float* Am = pass ? msg : x;
    const float* Bm = pass ? W11 : W10;
    for (int k0 = 0; k0 < F_DIM; k0 += 32) {
#pragma unroll
      for (int e = 0; e < 8; ++e) {
        int idx = tid + e * 256;
        int i = idx >> 5, kk = idx & 31;
        int gr = row0 + i;
        As[kk][i] = (gr < N_NODES) ? Am[(size_t)gr * F_DIM + k0 + kk] : 0.f;
      }
#pragma unroll
      for (int e = 0; e < 8; ++e) {
        int idx = tid + e * 256;
        int kk = idx >> 6, j = idx & 63;
        Bs[kk][j] = Bm[(size_t)(k0 + kk) * H_DIM + col0 + j];
      }
      __syncthreads();
#pragma unroll
      for (int kk = 0; kk < 32; ++kk) {
        float4 a = *(const float4*)&As[kk][ty * 4];
        float4 b = *(const float4*)&Bs[kk][tx * 4];
        float av[4] = {a.x, a.y, a.z, a.w};
        float bv[4] = {b.x, b.y, b.z, b.w};
#pragma unroll
        for (int ii = 0; ii < 4; ++ii)
#pragma unroll
          for (int jj = 0; jj < 4; ++jj) acc[ii][jj] += av[ii] * bv[jj];
      }
      __syncthreads();
    }
  }
#pragma unroll
  for (int ii = 0; ii < 4; ++ii) {
    int gr = row0 + ty * 4 + ii;
    if (gr < N_NODES) {
#pragma unroll
      for (int jj = 0; jj < 4; ++jj) {
        int c = col0 + tx * 4 + jj;
        float val = acc[ii][jj] + b1[c];
        h[(size_t)gr * H_DIM + c] = val > 0.f ? val : 0.f;
      }
    }
  }
}

// ---------------- GNN layer 2 (collapses to scalars) ----------------

// one wave per row: t[i]=h[i,:].W20, s[i]=h[i,:].W21
__global__ __launch_bounds__(256) void k_ts(const float* __restrict__ h,
    const float* __restrict__ W20, const float* __restrict__ W21,
    float* __restrict__ t, float* __restrict__ s) {
  int wid = (blockIdx.x * 256 + threadIdx.x) >> 6;
  int lane = threadIdx.x & 63;
  if (wid >= N_NODES) return;
  const float4* h4 = (const float4*)(h + (size_t)wid * H_DIM);
  float4 hv = h4[lane];
  float4 w0 = ((const float4*)W20)[lane];
  float4 w1 = ((const float4*)W21)[lane];
  float ta = hv.x * w0.x + hv.y * w0.y + hv.z * w0.z + hv.w * w0.w;
  float sa = hv.x * w1.x + hv.y * w1.y + hv.z * w1.z + hv.w * w1.w;
  ta = wred(ta);
  sa = wred(sa);
  if (lane == 0) { t[wid] = ta; s[wid] = sa; }
}

__global__ __launch_bounds__(256) void k_h2(const float* __restrict__ t,
    const float* __restrict__ s, const int* __restrict__ rowstart,
    const int* __restrict__ cols, const float* __restrict__ wvals,
    const float* __restrict__ lamb, const float* __restrict__ b2, float* __restrict__ h2) {
  int i = blockIdx.x * 256 + threadIdx.x;
  if (i >= N_NODES) return;
  float m = 0.f;
  int s0 = rowstart[i], s1 = rowstart[i + 1];
  for (int e = s0; e < s1; ++e) m += wvals[e] * s[cols[e]];
  float val = t[i] + m + b2[0];
  val = val > 0.f ? val : 0.f;
  h2[i] = lamb[0] * val;
}

// ---------------- QP setup ----------------

// btA_parts[by][j] = sum_{k in chunk by} A[k,j]*b[k]
__global__ __launch_bounds__(256) void k_btA(const float* __restrict__ A,
    const float* __restrict__ b, float* __restrict__ btA_parts) {
  int j = blockIdx.x * 256 + threadIdx.x;
  int k0 = blockIdx.y * 128;
  float acc = 0.f;
#pragma unroll 8
  for (int kk = 0; kk < 128; ++kk) acc += A[(size_t)(k0 + kk) * NQ + j] * b[k0 + kk];
  btA_parts[(size_t)blockIdx.y * NQ + j] = acc;
}

__global__ __launch_bounds__(256) void k_qrhs(const float* __restrict__ h2,
    const int* __restrict__ feat_ids, const float* __restrict__ x_prior,
    const float* __restrict__ btA_parts, float* __restrict__ q, float* __restrict__ rhs) {
  int j = blockIdx.x * 256 + threadIdx.x;
  int f = feat_ids[j];
  float hf = h2[f] + 1e-5f;
  q[j] = hf;
  float bta = 0.f;
#pragma unroll
  for (int c = 0; c < 32; ++c) bta += btA_parts[(size_t)c * NQ + j];
  rhs[j] = x_prior[j] * hf + bta;  // rhs = -p
}

// ---------------- CG: solve (A^T A + diag(q)) z = rhs ----------------

__global__ __launch_bounds__(256) void k_cginit(const float* __restrict__ rhs,
    float* __restrict__ r, float* __restrict__ pv, float* __restrict__ rr_parts) {
  __shared__ float lds[4];
  int j = blockIdx.x * 256 + threadIdx.x;
  float val = rhs[j];
  r[j] = val;
  pv[j] = val;
  float tot = bred256(val * val, lds);
  if (threadIdx.x == 0) rr_parts[blockIdx.x] = tot;
}

// v = A p : one wave per row of A
__global__ __launch_bounds__(256) void k_Ap(const float* __restrict__ A,
    const float* __restrict__ pv, float* __restrict__ v) {
  int wid = (blockIdx.x * 256 + threadIdx.x) >> 6;
  int lane = threadIdx.x & 63;
  const float4* Ar = (const float4*)(A + (size_t)wid * NQ);
  const float4* p4 = (const float4*)pv;
  float acc = 0.f;
#pragma unroll
  for (int st = 0; st < 8; ++st) {
    int idx = st * 64 + lane;
    float4 a = Ar[idx];
    float4 b = p4[idx];
    acc += a.x * b.x + a.y * b.y + a.z * b.z + a.w * b.w;
  }
  acc = wred(acc);
  if (lane == 0) v[wid] = acc;
}

// Qp_parts[by][j] = sum_{k in chunk} A[k,j]*v[k]; pAp partials per block
__global__ __launch_bounds__(256) void k_ATv(const float* __restrict__ A,
    const float* __restrict__ v, const float* __restrict__ pv, const float* __restrict__ q,
    float* __restrict__ Qp_parts, float* __restrict__ pAp_parts) {
  __shared__ float lds[4];
  int bx = blockIdx.x, by = blockIdx.y;
  int j = bx * 256 + threadIdx.x;
  int k0 = by * 128;
  float acc = 0.f;
#pragma unroll 8
  for (int kk = 0; kk < 128; ++kk) acc += A[(size_t)(k0 + kk) * NQ + j] * v[k0 + kk];
  Qp_parts[(size_t)by * NQ + j] = acc;
  float pj = pv[j];
  float contrib = pj * acc;
  if (by == 0) contrib += q[j] * pj * pj;  // adds p.(q*p) term once
  float tot = bred256(contrib, lds);
  if (threadIdx.x == 0) pAp_parts[by * 8 + bx] = tot;
}

__global__ __launch_bounds__(256) void k_update(int k, const float* __restrict__ Qp_parts,
    const float* __restrict__ pAp_parts, float* __restrict__ rr_parts,
    const float* __restrict__ q, const float* __restrict__ pv,
    float* __restrict__ xcg, float* __restrict__ rvec) {
  __shared__ float lds[4];
  int tx = threadIdx.x;
  int j = blockIdx.x * 256 + tx;
  float pAp = bred256(pAp_parts[tx], lds);
  float rro = bred256(tx < 8 ? rr_parts[k * 8 + tx] : 0.f, lds);
  float alpha = rro / pAp;
  float pj = pv[j];
  float Qpj = q[j] * pj;
#pragma unroll
  for (int c = 0; c < 32; ++c) Qpj += Qp_parts[(size_t)c * NQ + j];
  xcg[j] += alpha * pj;
  float rj = rvec[j] - alpha * Qpj;
  rvec[j] = rj;
  float rrn = bred256(rj * rj, lds);
  if (tx == 0) rr_parts[(k + 1) * 8 + blockIdx.x] = rrn;
}

__global__ __launch_bounds__(256) void k_pup(int k, const float* __restrict__ rr_parts,
    const float* __restrict__ rvec, float* __restrict__ pv) {
  int j = blockIdx.x * 256 + threadIdx.x;
  float rro = 0.f, rrn = 0.f;
#pragma unroll
  for (int i = 0; i < 8; ++i) {
    rro += rr_parts[k * 8 + i];
    rrn += rr_parts[(k + 1) * 8 + i];
  }
  float beta = rrn / rro;
  pv[j] = rvec[j] + beta * pv[j];
}

__global__ __launch_bounds__(256) void k_out(const float* __restrict__ xcg, float* __restrict__ out) {
  int j = blockIdx.x * 256 + threadIdx.x;
  out[j] = xcg[j];
}

// ---------------- launch ----------------

extern "C" void kernel_launch(void* const* d_in, const int* in_sizes, int n_in,
                              void* d_out, int out_size, void* d_ws, size_t ws_size,
                              hipStream_t stream) {
  const float* x      = (const float*)d_in[0];
  const int*   ei     = (const int*)d_in[1];
  const float* A      = (const float*)d_in[2];
  const float* b      = (const float*)d_in[3];
  const int*   fids   = (const int*)d_in[4];
  const float* xprior = (const float*)d_in[5];
  const float* lamb   = (const float*)d_in[6];
  const float* W10    = (const float*)d_in[7];
  const float* W11    = (const float*)d_in[8];
  const float* b1     = (const float*)d_in[9];
  const float* W20    = (const float*)d_in[10];
  const float* W21    = (const float*)d_in[11];
  const float* b2     = (const float*)d_in[12];
  float* out = (float*)d_out;

  char* base = (char*)d_ws;
  size_t o = 0;
  auto alloc = [&](size_t bytes) { size_t r = o; o = (o + bytes + 255) & ~size_t(255); return r; };

  // zero-init region first (deg, cursor, xcg)
  size_t off_deg    = alloc(N_NODES * 4);
  size_t off_cursor = alloc(N_NODES * 4);
  size_t off_xcg    = alloc(NQ * 4);
  size_t zero_end   = o;
  size_t off_rowst  = alloc((N_NODES + 1) * 4);
  size_t off_dinv   = alloc(N_NODES * 4);
  size_t off_cols   = alloc(N_EDGES * 4);
  size_t off_wvals  = alloc(N_EDGES * 4);
  size_t off_msg1   = alloc((size_t)N_NODES * F_DIM * 4);
  size_t off_h      = alloc((size_t)N_NODES * H_DIM * 4);
  size_t off_t      = alloc(N_NODES * 4);
  size_t off_s      = alloc(N_NODES * 4);
  size_t off_h2     = alloc(N_NODES * 4);
  size_t off_q      = alloc(NQ * 4);
  size_t off_rhs    = alloc(NQ * 4);
  size_t off_r      = alloc(NQ * 4);
  size_t off_pv     = alloc(NQ * 4);
  size_t off_v      = alloc(M_ROWS * 4);
  size_t off_btAp   = alloc(32 * NQ * 4);
  size_t off_Qpp    = alloc(32 * NQ * 4);
  size_t off_pApp   = alloc(256 * 4);
  size_t off_rrp    = alloc((NIT + 1) * 8 * 4);
  if (o > ws_size) return;  // workspace too small; validation will flag

  int*   deg      = (int*)(base + off_deg);
  int*   cursor   = (int*)(base + off_cursor);
  float* xcg      = (float*)(base + off_xcg);
  int*   rowstart = (int*)(base + off_rowst);
  float* dinv     = (float*)(base + off_dinv);
  int*   cols     = (int*)(base + off_cols);
  float* wvals    = (float*)(base + off_wvals);
  float* msg1     = (float*)(base + off_msg1);
  float* h        = (float*)(base + off_h);
  float* t        = (float*)(base + off_t);
  float* s        = (float*)(base + off_s);
  float* h2      = (float*)(base + off_h2);
  float* q        = (float*)(base + off_q);
  float* rhs      = (float*)(base + off_rhs);
  float* rvec     = (float*)(base + off_r);
  float* pv       = (float*)(base + off_pv);
  float* v        = (float*)(base + off_v);
  float* btA_parts = (float*)(base + off_btAp);
  float* Qp_parts  = (float*)(base + off_Qpp);
  float* pAp_parts = (float*)(base + off_pApp);
  float* rr_parts  = (float*)(base + off_rrp);

  hipMemsetAsync(d_ws, 0, zero_end, stream);

  // CSR build
  k_deg<<<(N_EDGES + 255) / 256, 256, 0, stream>>>(ei, deg);
  k_dinv<<<(N_NODES + 255) / 256, 256, 0, stream>>>(deg, dinv);
  k_scan<<<1, 1024, 0, stream>>>(deg, rowstart);
  k_scatter<<<(N_EDGES + 255) / 256, 256, 0, stream>>>(ei, rowstart, cursor, dinv, cols, wvals);

  // GNN layer 1
  k_msg1<<<N_NODES / 4, 256, 0, stream>>>(x, rowstart, cols, wvals, msg1);
  k_gemm1<<<dim3((N_NODES + 63) / 64, H_DIM / 64), 256, 0, stream>>>(x, msg1, W10, W11, b1, h);

  // GNN layer 2
  k_ts<<<N_NODES / 4, 256, 0, stream>>>(h, W20, W21, t, s);
  k_h2<<<(N_NODES + 255) / 256, 256, 0, stream>>>(t, s, rowstart, cols, wvals, lamb, b2, h2);

  // QP setup
  k_btA<<<dim3(NQ / 256, M_ROWS / 128), 256, 0, stream>>>(A, b, btA_parts);
  k_qrhs<<<NQ / 256, 256, 0, stream>>>(h2, fids, xprior, btA_parts, q, rhs);

  // CG
  k_cginit<<<NQ / 256, 256, 0, stream>>>(rhs, rvec, pv, rr_parts);
  for (int k = 0; k < NIT; ++k) {
    k_Ap<<<M_ROWS / 4, 256, 0, stream>>>(A, pv, v);
    k_ATv<<<dim3(NQ / 256, M_ROWS / 128), 256, 0, stream>>>(A, v, pv, q, Qp_parts, pAp_parts);
    k_update<<<NQ / 256, 256, 0, stream>>>(k, Qp_parts, pAp_parts, rr_parts, q, pv, xcg, rvec);
    k_pup<<<NQ / 256, 256, 0, stream>>>(k, rr_parts, rvec, pv);
  }

  k_out<<<NQ / 256, 256, 0, stream>>>(xcg, out);
}